// Round 4
// baseline (159.743 us; speedup 1.0000x reference)
//
#include <hip/hip_runtime.h>
#include <hip/hip_bf16.h>

// PerfectMemory: M_t = d*(I - a*k k^T) M_{t-1} + b*k v^T. Heads identical
// (M0=0) -> one 256x256 state; columns independent -> 1 wave per column.
// Blockwise-exact scan (B=64): b = K_blk M_s, (I+A)w = rhs (readlane forward
// substitution), M = d^64 M + K^T W~. K blocks double-buffered in LDS via
// global_load_lds (zero-VGPR staging); XOR swizzle applied on the GLOBAL
// source address (global_load_lds writes linearly), LDS reads use the same
// XOR -> conflict-free in both row-per-lane (A) and row-broadcast (C) phases.
// History truncated to last T steps (0.99^T << tol).

#define D_EMB 768
#define DK 256

static constexpr float DECAY = 0.99f;
static constexpr float AD    = 0.1f * 0.99f;   // alpha*decay

__device__ __forceinline__ float bcast_lane(float x, int lane) {
  return __int_as_float(__builtin_amdgcn_readlane(__float_as_int(x), lane));
}
__device__ __forceinline__ int SW(int r, int c4) { return c4 ^ (r & 15); }

// async global->LDS, 16B per lane; lds base must be wave-uniform.
__device__ __forceinline__ void gll16(const float4* g, float4* l) {
  __builtin_amdgcn_global_load_lds(
      (const __attribute__((address_space(1))) void*)g,
      (__attribute__((address_space(3))) void*)l, 16, 0, 0);
}

// ---------------- Kernel A: K/V projection (+ k row-normalize) --------------
__global__ __launch_bounds__(256) void gemm_kv(
    const float* __restrict__ emb, const float* __restrict__ Wk,
    const float* __restrict__ Wv, float* __restrict__ Kn,
    float* __restrict__ VT, int S, int T)
{
  __shared__ float se[8][D_EMB];
  __shared__ float sred[4][8];
  const int tid  = threadIdx.x;
  const int row0 = blockIdx.x * 8;
  const bool isV = (blockIdx.y != 0);
  const float* __restrict__ W = isV ? Wv : Wk;
  const long g0  = (long)(S - T + row0) * D_EMB;

  const float4* ef = (const float4*)(emb + g0);
  float4* sf = (float4*)(&se[0][0]);
  for (int i = tid; i < 8 * D_EMB / 4; i += 256) sf[i] = ef[i];
  __syncthreads();

  const int c = tid;
  float acc[8] = {0,0,0,0,0,0,0,0};

  for (int e = 0; e < D_EMB; e += 4) {
    float4 xv[8];
    #pragma unroll
    for (int r = 0; r < 8; ++r) xv[r] = *(const float4*)&se[r][e];
    #pragma unroll
    for (int q = 0; q < 4; ++q) {
      const float wq = W[(e + q) * DK + c];
      #pragma unroll
      for (int r = 0; r < 8; ++r)
        acc[r] = fmaf((&xv[r].x)[q], wq, acc[r]);
    }
  }

  if (!isV) {
    const int lane = tid & 63, wid = tid >> 6;
    float nrm[8];
    #pragma unroll
    for (int r = 0; r < 8; ++r) {
      float p = acc[r] * acc[r];
      p += __shfl_xor(p, 1, 64);  p += __shfl_xor(p, 2, 64);
      p += __shfl_xor(p, 4, 64);  p += __shfl_xor(p, 8, 64);
      p += __shfl_xor(p, 16, 64); p += __shfl_xor(p, 32, 64);
      nrm[r] = p;
    }
    if (lane == 0) {
      #pragma unroll
      for (int r = 0; r < 8; ++r) sred[wid][r] = nrm[r];
    }
    __syncthreads();
    #pragma unroll
    for (int r = 0; r < 8; ++r) {
      const float s   = sred[0][r] + sred[1][r] + sred[2][r] + sred[3][r];
      const float inv = 1.0f / fmaxf(sqrtf(s), 1e-12f);
      Kn[(row0 + r) * DK + c] = acc[r] * inv;
    }
  } else {
    float4 o0 = make_float4(acc[0], acc[1], acc[2], acc[3]);
    float4 o1 = make_float4(acc[4], acc[5], acc[6], acc[7]);
    *(float4*)&VT[(size_t)c * T + row0]     = o0;
    *(float4*)&VT[(size_t)c * T + row0 + 4] = o1;
  }
}

// ---------------- Kernel B: per-block Gram -> AT ------------------------------
// ATg[blk][j][t] = (t>j) ? -AD * d^(t-1-j) * (k_{t0+t}.k_{t0+j}) : 0
__global__ __launch_bounds__(256) void gram(const float* __restrict__ Kn,
                                            float* __restrict__ ATg, int T)
{
  __shared__ float4 Kl[64 * 64];
  const int blk = blockIdx.x, jq = blockIdx.y, t0 = blk << 6;
  const int tid = threadIdx.x, lane = tid & 63, wid = tid >> 6;
  const float4* Knf4 = (const float4*)Kn;

  {
    const int c4 = tid & 63, r0 = tid >> 6;
    #pragma unroll
    for (int m = 0; m < 16; ++m) {
      const int r = (m << 2) + r0;
      Kl[r * 64 + SW(r, c4)] = Knf4[((size_t)(t0 + r) << 6) + c4];
    }
  }
  __syncthreads();

  const int t = lane;
  const int jbase = (jq << 4) + (wid << 2);
  float a0 = 0.f, a1 = 0.f, a2 = 0.f, a3 = 0.f;
  for (int kk = 0; kk < 64; ++kk) {
    const float4 kt = Kl[t * 64 + SW(t, kk)];
    const float4 j0 = Kl[(jbase + 0) * 64 + SW(jbase + 0, kk)];
    const float4 j1 = Kl[(jbase + 1) * 64 + SW(jbase + 1, kk)];
    const float4 j2 = Kl[(jbase + 2) * 64 + SW(jbase + 2, kk)];
    const float4 j3 = Kl[(jbase + 3) * 64 + SW(jbase + 3, kk)];
    a0 = fmaf(kt.x, j0.x, a0); a0 = fmaf(kt.y, j0.y, a0);
    a0 = fmaf(kt.z, j0.z, a0); a0 = fmaf(kt.w, j0.w, a0);
    a1 = fmaf(kt.x, j1.x, a1); a1 = fmaf(kt.y, j1.y, a1);
    a1 = fmaf(kt.z, j1.z, a1); a1 = fmaf(kt.w, j1.w, a1);
    a2 = fmaf(kt.x, j2.x, a2); a2 = fmaf(kt.y, j2.y, a2);
    a2 = fmaf(kt.z, j2.z, a2); a2 = fmaf(kt.w, j2.w, a2);
    a3 = fmaf(kt.x, j3.x, a3); a3 = fmaf(kt.y, j3.y, a3);
    a3 = fmaf(kt.z, j3.z, a3); a3 = fmaf(kt.w, j3.w, a3);
  }

  float acc[4] = {a0, a1, a2, a3};
  #pragma unroll
  for (int i = 0; i < 4; ++i) {
    const int j = jbase + i;
    const float cf = (t > j) ? -AD * __powf(DECAY, (float)(t - 1 - j)) : 0.0f;
    ATg[((size_t)blk << 12) + (j << 6) + t] = cf * acc[i];
  }
}

// ---------------- Kernel C: blockwise scan, 1 wave per column ----------------
// One iteration; KCUR/KNXT are distinct __shared__ arrays (alias-analyzable).
#define SCAN_ITER(KCUR, KNXT, B)                                               \
  {                                                                            \
    const int t0 = (B) << 6;                                                   \
    const bool pf = ((B) + 1 < nblk);                                          \
    if (pf) {                                                                  \
      _Pragma("unroll")                                                        \
      for (int r = 0; r < 64; ++r)                                             \
        gll16(Knf4 + (((size_t)(t0 + 64 + r)) << 6) + (lane ^ (r & 15)),       \
              &KNXT[r * 64]);                                                  \
    }                                                                          \
    const float vt = VT[(size_t)v * T + t0 + lane];                            \
    Ml4[lane] = M;                                                             \
    M.x *= D64; M.y *= D64; M.z *= D64; M.w *= D64;                            \
    float bx = 0.f, by = 0.f, bz = 0.f, bw = 0.f;                              \
    _Pragma("unroll 16")                                                       \
    for (int jj = 0; jj < 64; ++jj) {                                          \
      const float4 kj = KCUR[rbase + (jj ^ lx)];                               \
      const float4 mj = Ml4[jj];                                               \
      bx = fmaf(kj.x, mj.x, bx); by = fmaf(kj.y, mj.y, by);                    \
      bz = fmaf(kj.z, mj.z, bz); bw = fmaf(kj.w, mj.w, bw);                    \
    }                                                                          \
    float w = vt - AD * dpl * ((bx + by) + (bz + bw));                         \
    _Pragma("unroll")                                                          \
    for (int j = 0; j < 63; ++j)                                               \
      w = fmaf(ATs[(j << 6) + lane], bcast_lane(w, j), w);                     \
    w *= drev;                                                                 \
    wl[lane] = w;                                                              \
    if (pf) {                                                                  \
      _Pragma("unroll")                                                        \
      for (int i = 0; i < 16; ++i)                                             \
        gll16(ATf4 + (((size_t)((B) + 1)) << 10) + (i << 6) + lane,            \
              &ATl4[i << 6]);                                                  \
    }                                                                          \
    _Pragma("unroll 16")                                                       \
    for (int t = 0; t < 64; ++t) {                                             \
      const float sw = wl[t];                                                  \
      const float4 kc = KCUR[t * 64 + (lane ^ (t & 15))];                      \
      M.x = fmaf(kc.x, sw, M.x); M.y = fmaf(kc.y, sw, M.y);                    \
      M.z = fmaf(kc.z, sw, M.z); M.w = fmaf(kc.w, sw, M.w);                    \
    }                                                                          \
    asm volatile("s_waitcnt vmcnt(0)" ::: "memory");                           \
  }

__global__ __launch_bounds__(64) void scan(
    const float* __restrict__ Kn, const float* __restrict__ VT,
    const float* __restrict__ ATg, float* __restrict__ Mcol, int T)
{
  __shared__ float4 KlA[4096];      // 64 KiB
  __shared__ float4 KlB[4096];      // 64 KiB
  __shared__ float4 ATl4[1024];     // 16 KiB, AT block [j][t]
  __shared__ float4 Ml4[64];
  __shared__ float  wl[64];

  const int v    = blockIdx.x;
  const int lane = threadIdx.x;
  const float4* Knf4 = (const float4*)Kn;
  const float4* ATf4 = (const float4*)ATg;
  const float*  ATs  = (const float*)ATl4;

  const float dpl  = __powf(DECAY, (float)lane);          // d^lane
  const float drev = __powf(DECAY, (float)(63 - lane));   // d^(63-lane)
  const float D64  = dpl * drev * DECAY;                  // d^64
  const int rbase  = lane * 64;
  const int lx     = lane & 15;

  float4 M = make_float4(0.f, 0.f, 0.f, 0.f);

  // prologue: stage K block 0 (pre-swizzled source) + AT block 0
  #pragma unroll
  for (int r = 0; r < 64; ++r)
    gll16(Knf4 + (((size_t)r) << 6) + (lane ^ (r & 15)), &KlA[r * 64]);
  #pragma unroll
  for (int i = 0; i < 16; ++i)
    gll16(ATf4 + (i << 6) + lane, &ATl4[i << 6]);
  asm volatile("s_waitcnt vmcnt(0)" ::: "memory");

  const int nblk = T >> 6;          // even (T multiple of 128)
  for (int bb = 0; bb < nblk; bb += 2) {
    SCAN_ITER(KlA, KlB, bb)
    SCAN_ITER(KlB, KlA, bb + 1)
  }

  ((float4*)Mcol)[v * 64 + lane] = M;
}

// ---------------- Kernel D: transpose Mcol[v][j] -> out[h][j][v] x 8 heads ---
__global__ __launch_bounds__(256) void expand(const float* __restrict__ Mcol,
                                              float* __restrict__ out)
{
  __shared__ float s[64][65];
  const int h    = blockIdx.x >> 4;
  const int tile = blockIdx.x & 15;
  const int j0 = (tile & 3) * 64, v0 = (tile >> 2) * 64;
  const int c = threadIdx.x & 63;
  const int r = threadIdx.x >> 6;
  #pragma unroll
  for (int rr = r; rr < 64; rr += 4)
    s[rr][c] = Mcol[(v0 + rr) * 256 + j0 + c];
  __syncthreads();
  #pragma unroll
  for (int rr = r; rr < 64; rr += 4)
    out[h * 65536 + (j0 + rr) * 256 + v0 + c] = s[c][rr];
}

extern "C" void kernel_launch(void* const* d_in, const int* in_sizes, int n_in,
                              void* d_out, int out_size, void* d_ws, size_t ws_size,
                              hipStream_t stream) {
  const float* emb = (const float*)d_in[0];
  const float* Wk  = (const float*)d_in[1];
  const float* Wv  = (const float*)d_in[2];
  float* out = (float*)d_out;

  const int S = in_sizes[0] / D_EMB;

  // Truncation window (multiple of 128 -> even block count).
  // 0.99^1024 tail ~1e-5 << 2.4e-2.
  int T = 1024;
  auto need = [](int t) {
    return ((size_t)t * 576 + 65536) * sizeof(float);
  };
  if (ws_size < need(T)) T = 768;
  if (ws_size < need(T)) T = 512;
  if (T > S) T = S & ~127;

  float* Kn   = (float*)d_ws;
  float* VT   = Kn + (size_t)T * 256;
  float* ATg  = VT + (size_t)T * 256;
  float* Mcol = ATg + (size_t)(T / 64) * 4096;

  gemm_kv<<<dim3(T / 8, 2), dim3(256), 0, stream>>>(emb, Wk, Wv, Kn, VT, S, T);
  gram   <<<dim3(T / 64, 4), dim3(256), 0, stream>>>(Kn, ATg, T);
  scan   <<<dim3(256), dim3(64), 0, stream>>>(Kn, VT, ATg, Mcol, T);
  expand <<<dim3(128), dim3(256), 0, stream>>>(Mcol, out);
}

// Round 5
// 128.980 us; speedup vs baseline: 1.2385x; 1.2385x over previous
//
#include <hip/hip_runtime.h>
#include <hip/hip_bf16.h>

// PerfectMemory: M_t = d*(I - a*k k^T) M_{t-1} + b*k v^T. Heads identical
// (M0=0) -> one 256x256 state; columns independent -> 1 wave per column.
// Blockwise-exact scan (B=64): b = K_blk M_s, (I+A)w = rhs (readlane forward
// substitution), M = d^64 M + K^T W~.
// r5: 4 waves per WG, one column per wave, shared double-buffered K LDS
// staged via global_load_lds (16 rows per wave), shared AT tile, barriers
// as drain points (m97 pattern). XOR swizzle on GLOBAL source, linear LDS.

#define D_EMB 768
#define DK 256

static constexpr float DECAY = 0.99f;
static constexpr float AD    = 0.1f * 0.99f;   // alpha*decay

__device__ __forceinline__ float bcast_lane(float x, int lane) {
  return __int_as_float(__builtin_amdgcn_readlane(__float_as_int(x), lane));
}
__device__ __forceinline__ int SW(int r, int c4) { return c4 ^ (r & 15); }

// async global->LDS, 16B per lane; lds base must be wave-uniform.
__device__ __forceinline__ void gll16(const float4* g, float4* l) {
  __builtin_amdgcn_global_load_lds(
      (const __attribute__((address_space(1))) void*)g,
      (__attribute__((address_space(3))) void*)l, 16, 0, 0);
}

// ---------------- Kernel A: K/V projection (+ k row-normalize) --------------
__global__ __launch_bounds__(256) void gemm_kv(
    const float* __restrict__ emb, const float* __restrict__ Wk,
    const float* __restrict__ Wv, float* __restrict__ Kn,
    float* __restrict__ VT, int S, int T)
{
  __shared__ float se[8][D_EMB];
  __shared__ float sred[4][8];
  const int tid  = threadIdx.x;
  const int row0 = blockIdx.x * 8;
  const bool isV = (blockIdx.y != 0);
  const float* __restrict__ W = isV ? Wv : Wk;
  const long g0  = (long)(S - T + row0) * D_EMB;

  const float4* ef = (const float4*)(emb + g0);
  float4* sf = (float4*)(&se[0][0]);
  for (int i = tid; i < 8 * D_EMB / 4; i += 256) sf[i] = ef[i];
  __syncthreads();

  const int c = tid;
  float acc[8] = {0,0,0,0,0,0,0,0};

  for (int e = 0; e < D_EMB; e += 4) {
    float4 xv[8];
    #pragma unroll
    for (int r = 0; r < 8; ++r) xv[r] = *(const float4*)&se[r][e];
    #pragma unroll
    for (int q = 0; q < 4; ++q) {
      const float wq = W[(e + q) * DK + c];
      #pragma unroll
      for (int r = 0; r < 8; ++r)
        acc[r] = fmaf((&xv[r].x)[q], wq, acc[r]);
    }
  }

  if (!isV) {
    const int lane = tid & 63, wid = tid >> 6;
    float nrm[8];
    #pragma unroll
    for (int r = 0; r < 8; ++r) {
      float p = acc[r] * acc[r];
      p += __shfl_xor(p, 1, 64);  p += __shfl_xor(p, 2, 64);
      p += __shfl_xor(p, 4, 64);  p += __shfl_xor(p, 8, 64);
      p += __shfl_xor(p, 16, 64); p += __shfl_xor(p, 32, 64);
      nrm[r] = p;
    }
    if (lane == 0) {
      #pragma unroll
      for (int r = 0; r < 8; ++r) sred[wid][r] = nrm[r];
    }
    __syncthreads();
    #pragma unroll
    for (int r = 0; r < 8; ++r) {
      const float s   = sred[0][r] + sred[1][r] + sred[2][r] + sred[3][r];
      const float inv = 1.0f / fmaxf(sqrtf(s), 1e-12f);
      Kn[(row0 + r) * DK + c] = acc[r] * inv;
    }
  } else {
    float4 o0 = make_float4(acc[0], acc[1], acc[2], acc[3]);
    float4 o1 = make_float4(acc[4], acc[5], acc[6], acc[7]);
    *(float4*)&VT[(size_t)c * T + row0]     = o0;
    *(float4*)&VT[(size_t)c * T + row0 + 4] = o1;
  }
}

// ---------------- Kernel B: per-block Gram -> AT ------------------------------
// ATg[blk][j][t] = (t>j) ? -AD * d^(t-1-j) * (k_{t0+t}.k_{t0+j}) : 0
__global__ __launch_bounds__(256) void gram(const float* __restrict__ Kn,
                                            float* __restrict__ ATg, int T)
{
  __shared__ float4 Kl[64 * 64];
  const int blk = blockIdx.x, jq = blockIdx.y, t0 = blk << 6;
  const int tid = threadIdx.x, lane = tid & 63, wid = tid >> 6;
  const float4* Knf4 = (const float4*)Kn;

  {
    const int c4 = tid & 63, r0 = tid >> 6;
    #pragma unroll
    for (int m = 0; m < 16; ++m) {
      const int r = (m << 2) + r0;
      Kl[r * 64 + SW(r, c4)] = Knf4[((size_t)(t0 + r) << 6) + c4];
    }
  }
  __syncthreads();

  const int t = lane;
  const int jbase = (jq << 4) + (wid << 2);
  float a0 = 0.f, a1 = 0.f, a2 = 0.f, a3 = 0.f;
  for (int kk = 0; kk < 64; ++kk) {
    const float4 kt = Kl[t * 64 + SW(t, kk)];
    const float4 j0 = Kl[(jbase + 0) * 64 + SW(jbase + 0, kk)];
    const float4 j1 = Kl[(jbase + 1) * 64 + SW(jbase + 1, kk)];
    const float4 j2 = Kl[(jbase + 2) * 64 + SW(jbase + 2, kk)];
    const float4 j3 = Kl[(jbase + 3) * 64 + SW(jbase + 3, kk)];
    a0 = fmaf(kt.x, j0.x, a0); a0 = fmaf(kt.y, j0.y, a0);
    a0 = fmaf(kt.z, j0.z, a0); a0 = fmaf(kt.w, j0.w, a0);
    a1 = fmaf(kt.x, j1.x, a1); a1 = fmaf(kt.y, j1.y, a1);
    a1 = fmaf(kt.z, j1.z, a1); a1 = fmaf(kt.w, j1.w, a1);
    a2 = fmaf(kt.x, j2.x, a2); a2 = fmaf(kt.y, j2.y, a2);
    a2 = fmaf(kt.z, j2.z, a2); a2 = fmaf(kt.w, j2.w, a2);
    a3 = fmaf(kt.x, j3.x, a3); a3 = fmaf(kt.y, j3.y, a3);
    a3 = fmaf(kt.z, j3.z, a3); a3 = fmaf(kt.w, j3.w, a3);
  }

  float acc[4] = {a0, a1, a2, a3};
  #pragma unroll
  for (int i = 0; i < 4; ++i) {
    const int j = jbase + i;
    const float cf = (t > j) ? -AD * __powf(DECAY, (float)(t - 1 - j)) : 0.0f;
    ATg[((size_t)blk << 12) + (j << 6) + t] = cf * acc[i];
  }
}

// ---------------- Kernel C: blockwise scan ----------------------------------
// 4 waves per WG, one column per wave; shared K dbuf + AT tile.
#define SCAN_ITER(KCUR, KNXT, B)                                               \
  {                                                                            \
    const int t0 = (B) << 6;                                                   \
    const bool pf = ((B) + 1 < nblk);                                          \
    const float vt = VT[(size_t)v * T + t0 + lane];   /* before glls! */       \
    if (pf) {                                                                  \
      _Pragma("unroll")                                                        \
      for (int rr = 0; rr < 16; ++rr) {                                        \
        const int r = (wid << 4) + rr;                                         \
        gll16(Knf4 + (((size_t)(t0 + 64 + r)) << 6) + (lane ^ (r & 15)),       \
              &KNXT[r * 64]);                                                  \
      }                                                                        \
    }                                                                          \
    Mw[lane] = M;                                                              \
    M.x *= D64; M.y *= D64; M.z *= D64; M.w *= D64;                            \
    float bx = 0.f, by = 0.f, bz = 0.f, bw = 0.f;                              \
    _Pragma("unroll 16")                                                       \
    for (int jj = 0; jj < 64; ++jj) {                                          \
      const float4 kj = KCUR[rbase + (jj ^ lx)];                               \
      const float4 mj = Mw[jj];                                                \
      bx = fmaf(kj.x, mj.x, bx); by = fmaf(kj.y, mj.y, by);                    \
      bz = fmaf(kj.z, mj.z, bz); bw = fmaf(kj.w, mj.w, bw);                    \
    }                                                                          \
    float w = vt - AD * dpl * ((bx + by) + (bz + bw));                         \
    _Pragma("unroll")                                                          \
    for (int j = 0; j < 63; ++j)                                               \
      w = fmaf(ATs[(j << 6) + lane], bcast_lane(w, j), w);                     \
    w *= drev;                                                                 \
    wlw[lane] = w;                                                             \
    __syncthreads();   /* all waves done reading ATl; K-next mostly landed */  \
    if (pf) {                                                                  \
      _Pragma("unroll")                                                        \
      for (int ii = 0; ii < 4; ++ii) {                                         \
        const int i = (wid << 2) + ii;                                         \
        gll16(ATf4 + (((size_t)((B) + 1)) << 10) + (i << 6) + lane,            \
              &ATl4[i << 6]);                                                  \
      }                                                                        \
    }                                                                          \
    _Pragma("unroll 16")                                                       \
    for (int t = 0; t < 64; ++t) {                                             \
      const float sw = wlw[t];                                                 \
      const float4 kc = KCUR[t * 64 + (lane ^ (t & 15))];                      \
      M.x = fmaf(kc.x, sw, M.x); M.y = fmaf(kc.y, sw, M.y);                    \
      M.z = fmaf(kc.z, sw, M.z); M.w = fmaf(kc.w, sw, M.w);                    \
    }                                                                          \
    __syncthreads();   /* drain K-next + AT-next; KCUR now reusable */         \
  }

__global__ __launch_bounds__(256) void scan(
    const float* __restrict__ Kn, const float* __restrict__ VT,
    const float* __restrict__ ATg, float* __restrict__ Mcol, int T)
{
  __shared__ float4 KlA[4096];        // 64 KiB
  __shared__ float4 KlB[4096];        // 64 KiB
  __shared__ float4 ATl4[1024];       // 16 KiB, AT block [j][t]
  __shared__ float4 Ml4[4][64];       // per-wave M_start exposure
  __shared__ float  wl[4][64];        // per-wave w

  const int tid  = threadIdx.x;
  const int lane = tid & 63;
  const int wid  = tid >> 6;
  const int v    = blockIdx.x * 4 + wid;      // column for this wave
  const float4* Knf4 = (const float4*)Kn;
  const float4* ATf4 = (const float4*)ATg;
  const float*  ATs  = (const float*)ATl4;
  float4* Mw  = Ml4[wid];
  float*  wlw = wl[wid];

  const float dpl  = __powf(DECAY, (float)lane);          // d^lane
  const float drev = __powf(DECAY, (float)(63 - lane));   // d^(63-lane)
  const float D64  = dpl * drev * DECAY;                  // d^64
  const int rbase  = lane * 64;
  const int lx     = lane & 15;

  float4 M = make_float4(0.f, 0.f, 0.f, 0.f);

  // prologue: stage K block 0 (16 rows per wave) + AT block 0 (4 rows/wave)
  #pragma unroll
  for (int rr = 0; rr < 16; ++rr) {
    const int r = (wid << 4) + rr;
    gll16(Knf4 + (((size_t)r) << 6) + (lane ^ (r & 15)), &KlA[r * 64]);
  }
  #pragma unroll
  for (int ii = 0; ii < 4; ++ii) {
    const int i = (wid << 2) + ii;
    gll16(ATf4 + (i << 6) + lane, &ATl4[i << 6]);
  }
  __syncthreads();

  const int nblk = T >> 6;            // even (T multiple of 128)
  for (int bb = 0; bb < nblk; bb += 2) {
    SCAN_ITER(KlA, KlB, bb)
    SCAN_ITER(KlB, KlA, bb + 1)
  }

  ((float4*)Mcol)[v * 64 + lane] = M;
}

// ---------------- Kernel D: transpose Mcol[v][j] -> out[h][j][v] x 8 heads ---
__global__ __launch_bounds__(256) void expand(const float* __restrict__ Mcol,
                                              float* __restrict__ out)
{
  __shared__ float s[64][65];
  const int h    = blockIdx.x >> 4;
  const int tile = blockIdx.x & 15;
  const int j0 = (tile & 3) * 64, v0 = (tile >> 2) * 64;
  const int c = threadIdx.x & 63;
  const int r = threadIdx.x >> 6;
  #pragma unroll
  for (int rr = r; rr < 64; rr += 4)
    s[rr][c] = Mcol[(v0 + rr) * 256 + j0 + c];
  __syncthreads();
  #pragma unroll
  for (int rr = r; rr < 64; rr += 4)
    out[h * 65536 + (j0 + rr) * 256 + v0 + c] = s[c][rr];
}

extern "C" void kernel_launch(void* const* d_in, const int* in_sizes, int n_in,
                              void* d_out, int out_size, void* d_ws, size_t ws_size,
                              hipStream_t stream) {
  const float* emb = (const float*)d_in[0];
  const float* Wk  = (const float*)d_in[1];
  const float* Wv  = (const float*)d_in[2];
  float* out = (float*)d_out;

  const int S = in_sizes[0] / D_EMB;

  // Truncation window (multiple of 128 -> even block count).
  // 0.99^1024 tail ~1e-5 << 2.4e-2.
  int T = 1024;
  auto need = [](int t) {
    return ((size_t)t * 576 + 65536) * sizeof(float);
  };
  if (ws_size < need(T)) T = 768;
  if (ws_size < need(T)) T = 512;
  if (T > S) T = S & ~127;

  float* Kn   = (float*)d_ws;
  float* VT   = Kn + (size_t)T * 256;
  float* ATg  = VT + (size_t)T * 256;
  float* Mcol = ATg + (size_t)(T / 64) * 4096;

  gemm_kv<<<dim3(T / 8, 2), dim3(256), 0, stream>>>(emb, Wk, Wv, Kn, VT, S, T);
  gram   <<<dim3(T / 64, 4), dim3(256), 0, stream>>>(Kn, ATg, T);
  scan   <<<dim3(64), dim3(256), 0, stream>>>(Kn, VT, ATg, Mcol, T);
  expand <<<dim3(128), dim3(256), 0, stream>>>(Mcol, out);
}

// Round 6
// 86.298 us; speedup vs baseline: 1.8511x; 1.4946x over previous
//
#include <hip/hip_runtime.h>
#include <hip/hip_bf16.h>

// PerfectMemory: M_t = d*(I - a*k k^T) M_{t-1} + b*k v^T. Heads identical
// (M0=0) -> one 256x256 state; columns independent -> 1 column per CU.
// Blockwise-exact scan (B=64): b = K_blk M_s, (I+A)w = rhs (readlane forward
// substitution), M = d^64 M + K^T W~.
// r6: 256 WGs x 2 waves. Wave1 = DMA producer (global_load_lds K-next/AT-next,
// drains its own vmcnt before the end barrier). Wave0 = consumer, never waits
// on vmem. M- and w-broadcasts via v_readlane from the consumer's registers
// (no LDS round-trip): LDS pipe per iter = 128 b128 (K twice) + 63 b32 (AT).
// XOR swizzle on the GLOBAL source address, linear LDS dest (T2/m173).

#define D_EMB 768
#define DK 256

static constexpr float DECAY = 0.99f;
static constexpr float AD    = 0.1f * 0.99f;   // alpha*decay

__device__ __forceinline__ float bcast_lane(float x, int lane) {
  return __int_as_float(__builtin_amdgcn_readlane(__float_as_int(x), lane));
}
__device__ __forceinline__ int SW(int r, int c4) { return c4 ^ (r & 15); }

#define BAR() asm volatile("s_barrier" ::: "memory")

// async global->LDS, 16B per lane; lds base must be wave-uniform.
__device__ __forceinline__ void gll16(const float4* g, float4* l) {
  __builtin_amdgcn_global_load_lds(
      (const __attribute__((address_space(1))) void*)g,
      (__attribute__((address_space(3))) void*)l, 16, 0, 0);
}

// ---------------- Kernel A: K/V projection (+ k row-normalize) --------------
__global__ __launch_bounds__(256) void gemm_kv(
    const float* __restrict__ emb, const float* __restrict__ Wk,
    const float* __restrict__ Wv, float* __restrict__ Kn,
    float* __restrict__ VT, int S, int T)
{
  __shared__ float se[8][D_EMB];
  __shared__ float sred[4][8];
  const int tid  = threadIdx.x;
  const int row0 = blockIdx.x * 8;
  const bool isV = (blockIdx.y != 0);
  const float* __restrict__ W = isV ? Wv : Wk;
  const long g0  = (long)(S - T + row0) * D_EMB;

  const float4* ef = (const float4*)(emb + g0);
  float4* sf = (float4*)(&se[0][0]);
  for (int i = tid; i < 8 * D_EMB / 4; i += 256) sf[i] = ef[i];
  __syncthreads();

  const int c = tid;
  float acc[8] = {0,0,0,0,0,0,0,0};

  for (int e = 0; e < D_EMB; e += 4) {
    float4 xv[8];
    #pragma unroll
    for (int r = 0; r < 8; ++r) xv[r] = *(const float4*)&se[r][e];
    #pragma unroll
    for (int q = 0; q < 4; ++q) {
      const float wq = W[(e + q) * DK + c];
      #pragma unroll
      for (int r = 0; r < 8; ++r)
        acc[r] = fmaf((&xv[r].x)[q], wq, acc[r]);
    }
  }

  if (!isV) {
    const int lane = tid & 63, wid = tid >> 6;
    float nrm[8];
    #pragma unroll
    for (int r = 0; r < 8; ++r) {
      float p = acc[r] * acc[r];
      p += __shfl_xor(p, 1, 64);  p += __shfl_xor(p, 2, 64);
      p += __shfl_xor(p, 4, 64);  p += __shfl_xor(p, 8, 64);
      p += __shfl_xor(p, 16, 64); p += __shfl_xor(p, 32, 64);
      nrm[r] = p;
    }
    if (lane == 0) {
      #pragma unroll
      for (int r = 0; r < 8; ++r) sred[wid][r] = nrm[r];
    }
    __syncthreads();
    #pragma unroll
    for (int r = 0; r < 8; ++r) {
      const float s   = sred[0][r] + sred[1][r] + sred[2][r] + sred[3][r];
      const float inv = 1.0f / fmaxf(sqrtf(s), 1e-12f);
      Kn[(row0 + r) * DK + c] = acc[r] * inv;
    }
  } else {
    float4 o0 = make_float4(acc[0], acc[1], acc[2], acc[3]);
    float4 o1 = make_float4(acc[4], acc[5], acc[6], acc[7]);
    *(float4*)&VT[(size_t)c * T + row0]     = o0;
    *(float4*)&VT[(size_t)c * T + row0 + 4] = o1;
  }
}

// ---------------- Kernel B: per-block Gram -> AT ------------------------------
// ATg[blk][j][t] = (t>j) ? -AD * d^(t-1-j) * (k_{t0+t}.k_{t0+j}) : 0
__global__ __launch_bounds__(256) void gram(const float* __restrict__ Kn,
                                            float* __restrict__ ATg, int T)
{
  __shared__ float4 Kl[64 * 64];
  const int blk = blockIdx.x, jq = blockIdx.y, t0 = blk << 6;
  const int tid = threadIdx.x, lane = tid & 63, wid = tid >> 6;
  const float4* Knf4 = (const float4*)Kn;

  {
    const int c4 = tid & 63, r0 = tid >> 6;
    #pragma unroll
    for (int m = 0; m < 16; ++m) {
      const int r = (m << 2) + r0;
      Kl[r * 64 + SW(r, c4)] = Knf4[((size_t)(t0 + r) << 6) + c4];
    }
  }
  __syncthreads();

  const int t = lane;
  const int jbase = (jq << 4) + (wid << 2);
  float a0 = 0.f, a1 = 0.f, a2 = 0.f, a3 = 0.f;
  for (int kk = 0; kk < 64; ++kk) {
    const float4 kt = Kl[t * 64 + SW(t, kk)];
    const float4 j0 = Kl[(jbase + 0) * 64 + SW(jbase + 0, kk)];
    const float4 j1 = Kl[(jbase + 1) * 64 + SW(jbase + 1, kk)];
    const float4 j2 = Kl[(jbase + 2) * 64 + SW(jbase + 2, kk)];
    const float4 j3 = Kl[(jbase + 3) * 64 + SW(jbase + 3, kk)];
    a0 = fmaf(kt.x, j0.x, a0); a0 = fmaf(kt.y, j0.y, a0);
    a0 = fmaf(kt.z, j0.z, a0); a0 = fmaf(kt.w, j0.w, a0);
    a1 = fmaf(kt.x, j1.x, a1); a1 = fmaf(kt.y, j1.y, a1);
    a1 = fmaf(kt.z, j1.z, a1); a1 = fmaf(kt.w, j1.w, a1);
    a2 = fmaf(kt.x, j2.x, a2); a2 = fmaf(kt.y, j2.y, a2);
    a2 = fmaf(kt.z, j2.z, a2); a2 = fmaf(kt.w, j2.w, a2);
    a3 = fmaf(kt.x, j3.x, a3); a3 = fmaf(kt.y, j3.y, a3);
    a3 = fmaf(kt.z, j3.z, a3); a3 = fmaf(kt.w, j3.w, a3);
  }

  float acc[4] = {a0, a1, a2, a3};
  #pragma unroll
  for (int i = 0; i < 4; ++i) {
    const int j = jbase + i;
    const float cf = (t > j) ? -AD * __powf(DECAY, (float)(t - 1 - j)) : 0.0f;
    ATg[((size_t)blk << 12) + (j << 6) + t] = cf * acc[i];
  }
}

// ---------------- Kernel C: blockwise scan, producer/consumer ---------------
// Consumer iteration: phase A uses PRE-decay M via readlane; solve; decay M;
// phase C accumulates. Barriers: mid (after solve / after K-next issue),
// end (after C / after producer's vmcnt(0) drain).
#define CONS_ITER(KCUR, B)                                                     \
  {                                                                            \
    const int t0 = (B) << 6;                                                   \
    const float vt = VT[(size_t)v * T + t0 + lane];                            \
    float bx = 0.f, by = 0.f, bz = 0.f, bw = 0.f;                              \
    _Pragma("unroll")                                                          \
    for (int jj = 0; jj < 64; ++jj) {                                          \
      const float4 kj = KCUR[rbase + (jj ^ lx)];                               \
      const float mx = bcast_lane(M.x, jj);                                    \
      const float my = bcast_lane(M.y, jj);                                    \
      const float mz = bcast_lane(M.z, jj);                                    \
      const float mw = bcast_lane(M.w, jj);                                    \
      bx = fmaf(kj.x, mx, bx); by = fmaf(kj.y, my, by);                        \
      bz = fmaf(kj.z, mz, bz); bw = fmaf(kj.w, mw, bw);                        \
    }                                                                          \
    float w = vt - AD * dpl * ((bx + by) + (bz + bw));                         \
    _Pragma("unroll")                                                          \
    for (int j = 0; j < 63; ++j)                                               \
      w = fmaf(ATs[(j << 6) + lane], bcast_lane(w, j), w);                     \
    w *= drev;                                                                 \
    BAR(); /* mid: AT reads done; producer may overwrite AT */                 \
    M.x *= D64; M.y *= D64; M.z *= D64; M.w *= D64;                            \
    _Pragma("unroll")                                                          \
    for (int t = 0; t < 64; ++t) {                                             \
      const float sw  = bcast_lane(w, t);                                      \
      const float4 kc = KCUR[t * 64 + (lane ^ (t & 15))];                      \
      M.x = fmaf(kc.x, sw, M.x); M.y = fmaf(kc.y, sw, M.y);                    \
      M.z = fmaf(kc.z, sw, M.z); M.w = fmaf(kc.w, sw, M.w);                    \
    }                                                                          \
    BAR(); /* end: next K/AT drained by producer */                            \
  }

#define PROD_ITER(KNXT, B)                                                     \
  {                                                                            \
    const int t0 = (B) << 6;                                                   \
    const bool pf = ((B) + 1 < nblk);                                          \
    if (pf) {                                                                  \
      _Pragma("unroll")                                                        \
      for (int r = 0; r < 64; ++r)                                             \
        gll16(Knf4 + (((size_t)(t0 + 64 + r)) << 6) + (lane ^ (r & 15)),       \
              &KNXT[r * 64]);                                                  \
    }                                                                          \
    BAR(); /* mid: consumer done with AT */                                    \
    if (pf) {                                                                  \
      _Pragma("unroll")                                                        \
      for (int i = 0; i < 16; ++i)                                             \
        gll16(ATf4 + (((size_t)((B) + 1)) << 10) + (i << 6) + lane,            \
              &ATl4[i << 6]);                                                  \
    }                                                                          \
    asm volatile("s_waitcnt vmcnt(0)" ::: "memory");                           \
    BAR(); /* end */                                                           \
  }

__global__ __launch_bounds__(128) void scan(
    const float* __restrict__ Kn, const float* __restrict__ VT,
    const float* __restrict__ ATg, float* __restrict__ Mcol, int T)
{
  __shared__ float4 KlA[4096];        // 64 KiB
  __shared__ float4 KlB[4096];        // 64 KiB
  __shared__ float4 ATl4[1024];       // 16 KiB, AT block [j][t]

  const int tid  = threadIdx.x;
  const int lane = tid & 63;
  const int wid  = tid >> 6;
  const int v    = blockIdx.x;                // column for this WG
  const float4* Knf4 = (const float4*)Kn;
  const float4* ATf4 = (const float4*)ATg;
  const float*  ATs  = (const float*)ATl4;

  const int nblk = T >> 6;            // even (T multiple of 128)

  if (wid == 1) {
    // ---------------- producer wave ----------------
    #pragma unroll
    for (int r = 0; r < 64; ++r)
      gll16(Knf4 + (((size_t)r) << 6) + (lane ^ (r & 15)), &KlA[r * 64]);
    #pragma unroll
    for (int i = 0; i < 16; ++i)
      gll16(ATf4 + (i << 6) + lane, &ATl4[i << 6]);
    asm volatile("s_waitcnt vmcnt(0)" ::: "memory");
    BAR(); /* prologue */
    for (int bb = 0; bb < nblk; bb += 2) {
      PROD_ITER(KlB, bb)
      PROD_ITER(KlA, bb + 1)
    }
  } else {
    // ---------------- consumer wave ----------------
    const float dpl  = __powf(DECAY, (float)lane);          // d^lane
    const float drev = __powf(DECAY, (float)(63 - lane));   // d^(63-lane)
    const float D64  = dpl * drev * DECAY;                  // d^64
    const int rbase  = lane * 64;
    const int lx     = lane & 15;
    float4 M = make_float4(0.f, 0.f, 0.f, 0.f);

    BAR(); /* prologue */
    for (int bb = 0; bb < nblk; bb += 2) {
      CONS_ITER(KlA, bb)
      CONS_ITER(KlB, bb + 1)
    }
    ((float4*)Mcol)[v * 64 + lane] = M;
  }
}

// ---------------- Kernel D: transpose Mcol[v][j] -> out[h][j][v] x 8 heads ---
__global__ __launch_bounds__(256) void expand(const float* __restrict__ Mcol,
                                              float* __restrict__ out)
{
  __shared__ float s[64][65];
  const int h    = blockIdx.x >> 4;
  const int tile = blockIdx.x & 15;
  const int j0 = (tile & 3) * 64, v0 = (tile >> 2) * 64;
  const int c = threadIdx.x & 63;
  const int r = threadIdx.x >> 6;
  #pragma unroll
  for (int rr = r; rr < 64; rr += 4)
    s[rr][c] = Mcol[(v0 + rr) * 256 + j0 + c];
  __syncthreads();
  #pragma unroll
  for (int rr = r; rr < 64; rr += 4)
    out[h * 65536 + (j0 + rr) * 256 + v0 + c] = s[c][rr];
}

extern "C" void kernel_launch(void* const* d_in, const int* in_sizes, int n_in,
                              void* d_out, int out_size, void* d_ws, size_t ws_size,
                              hipStream_t stream) {
  const float* emb = (const float*)d_in[0];
  const float* Wk  = (const float*)d_in[1];
  const float* Wv  = (const float*)d_in[2];
  float* out = (float*)d_out;

  const int S = in_sizes[0] / D_EMB;

  // Truncation window (multiple of 128 -> even block count).
  // 0.99^1024 tail ~1e-3 effect; measured absmax 3.9e-3 << 2.39e-2.
  int T = 1024;
  auto need = [](int t) {
    return ((size_t)t * 576 + 65536) * sizeof(float);
  };
  if (ws_size < need(T)) T = 768;
  if (ws_size < need(T)) T = 512;
  if (T > S) T = S & ~127;

  float* Kn   = (float*)d_ws;
  float* VT   = Kn + (size_t)T * 256;
  float* ATg  = VT + (size_t)T * 256;
  float* Mcol = ATg + (size_t)(T / 64) * 4096;

  gemm_kv<<<dim3(T / 8, 2), dim3(256), 0, stream>>>(emb, Wk, Wv, Kn, VT, S, T);
  gram   <<<dim3(T / 64, 4), dim3(256), 0, stream>>>(Kn, ATg, T);
  scan   <<<dim3(256), dim3(128), 0, stream>>>(Kn, VT, ATg, Mcol, T);
  expand <<<dim3(128), dim3(256), 0, stream>>>(Mcol, out);
}